// Round 3
// baseline (242.354 us; speedup 1.0000x reference)
//
#include <hip/hip_runtime.h>

// NMS 2D, 3x3 window, replicate padding, center excluded, max seeded with 0.
// x: (8, 64, 256, 256) fp32.  out[p] = x[p] if x[p] > max(0, 8 neighbors) else 0.
//
// R10: pipelined vertical walk. History:
//   R7 (1 row/thread, loop-free)            ~66 us
//   R8 (4 rows/thread, straight-line)       ~69 us  (issue-halving NEUTRAL)
//   R9 (R8 + nontemporal stores)            ~80 us  (REGRESSED; FETCH dropped
//        to 67 MB but store path lost L2 write-combining -> reverted)
// R9 counters: VALU 11%, HBM 31%, occ 67% -- nothing saturated, yet waves
// live ~30K cycles. Queues are full behind a ~4 TB/s service point. The
// burst-then-die wave shape pays full memory latency per wave with no
// pipelining; R1-R4's loops serialized on in-order vmcnt (load-wait drained
// prior stores). Fix both: each wave walks a 16-row strip in 4 steps with
// loads for step i+1 issued BEFORE step i's stores, so every load-wait has
// only younger loads/stores behind it in the vmcnt queue -- stores never
// block. Rolling register window (raw row + 2 HVs) cuts vertical read
// amplification to 18/16 = 1.125x. Normal stores (R9 reverted).

#define NMS_H 256
#define NMS_W 256
#define PLANE (NMS_H * NMS_W)
#define GRID_BLOCKS 2048   // 512 planes * 4 quarters; 4 waves/block = 8192 strips

typedef float f4_t __attribute__((ext_vector_type(4)));

struct HV {
    float4 h;   // horizontal max-of-3 per pixel (includes center)
    float4 lr;  // horizontal max of left+right only (center excluded)
};

__device__ __forceinline__ HV rowmax(const float4 v, const int tx) {
    float l = __shfl_up(v.w, 1, 64);    // last elem of lane tx-1
    float r = __shfl_down(v.x, 1, 64);  // first elem of lane tx+1
    if (tx == 0)  l = v.x;              // replicate pad left edge
    if (tx == 63) r = v.w;              // replicate pad right edge
    HV o;
    o.h.x = fmaxf(l,   fmaxf(v.x, v.y));
    o.h.y = fmaxf(v.x, fmaxf(v.y, v.z));
    o.h.z = fmaxf(v.y, fmaxf(v.z, v.w));
    o.h.w = fmaxf(v.z, fmaxf(v.w, r));
    o.lr.x = fmaxf(l,   v.y);
    o.lr.y = fmaxf(v.x, v.z);
    o.lr.z = fmaxf(v.y, v.w);
    o.lr.w = fmaxf(v.z, r);
    return o;
}

// m = max(0, h(row above), h(row below), lr(own row)); keep vc if strictly greater.
__device__ __forceinline__ f4_t nmspick(const float4 vc, const float4 ha,
                                        const float4 hb, const float4 lrc) {
    f4_t o;
    float m;
    m = fmaxf(0.0f, fmaxf(fmaxf(ha.x, hb.x), lrc.x)); o.x = (vc.x > m) ? vc.x : 0.0f;
    m = fmaxf(0.0f, fmaxf(fmaxf(ha.y, hb.y), lrc.y)); o.y = (vc.y > m) ? vc.y : 0.0f;
    m = fmaxf(0.0f, fmaxf(fmaxf(ha.z, hb.z), lrc.z)); o.z = (vc.z > m) ? vc.z : 0.0f;
    m = fmaxf(0.0f, fmaxf(fmaxf(ha.w, hb.w), lrc.w)); o.w = (vc.w > m) ? vc.w : 0.0f;
    return o;
}

// One 4-row step: v1..v4 = rows r+1..r+4 (already loaded).
// Carries in/out: vr = raw row r, hA = h(r-1).h, hC = HV(row r).
__device__ __forceinline__ void nms_step(const float4 v1, const float4 v2,
                                         const float4 v3, const float4 v4,
                                         float4& vr, float4& hA, HV& hC,
                                         float* __restrict__ po, const int r,
                                         const int tx) {
    const HV h1 = rowmax(v1, tx);
    const HV h2 = rowmax(v2, tx);
    const HV h3 = rowmax(v3, tx);
    const HV h4 = rowmax(v4, tx);
    *reinterpret_cast<f4_t*>(po + (r + 0) * NMS_W) = nmspick(vr, hA,   h1.h, hC.lr);
    *reinterpret_cast<f4_t*>(po + (r + 1) * NMS_W) = nmspick(v1, hC.h, h2.h, h1.lr);
    *reinterpret_cast<f4_t*>(po + (r + 2) * NMS_W) = nmspick(v2, h1.h, h3.h, h2.lr);
    *reinterpret_cast<f4_t*>(po + (r + 3) * NMS_W) = nmspick(v3, h2.h, h4.h, h3.lr);
    vr = v4;        // next step's center row r+4
    hA = h3.h;      // row above it
    hC = h4;        // its own HV
}

__global__ __launch_bounds__(256, 4) void nms2d_kernel(const float* __restrict__ x,
                                                       float* __restrict__ out) {
    // XCD swizzle: blocks dispatch round-robin across 8 XCDs (blk % 8).
    // Remap so XCD k owns planes [k*64, (k+1)*64) -> halo re-reads stay in
    // that XCD's L2. 2048 % 8 == 0 -> bijective.
    const int blk     = blockIdx.x;
    const int logical = (blk >> 3) + (blk & 7) * (GRID_BLOCKS / 8);

    const int plane_idx = logical >> 2;              // 512 planes
    const int quarter   = logical & 3;               // 64-row quarter
    const int w         = threadIdx.x >> 6;          // wave in block
    const int tx        = threadIdx.x & 63;          // float4 column-group
    const int R0        = quarter * 64 + w * 16;     // strip start row
    const int col4      = tx * 4;

    const float* pl = x   + (size_t)plane_idx * PLANE + col4;
    float*       po = out + (size_t)plane_idx * PLANE + col4;

    // Prologue: rows R0-1 (clamped), R0, and step-0's rows R0+1..R0+4.
    const int rm = max(R0 - 1, 0);
    const float4 vm = *reinterpret_cast<const float4*>(pl + rm       * NMS_W);
    float4 vr       = *reinterpret_cast<const float4*>(pl + R0       * NMS_W);
    const float4 a1 = *reinterpret_cast<const float4*>(pl + (R0 + 1) * NMS_W);
    const float4 a2 = *reinterpret_cast<const float4*>(pl + (R0 + 2) * NMS_W);
    const float4 a3 = *reinterpret_cast<const float4*>(pl + (R0 + 3) * NMS_W);
    const float4 a4 = *reinterpret_cast<const float4*>(pl + (R0 + 4) * NMS_W);

    float4 hA = rowmax(vm, tx).h;
    HV     hC = rowmax(vr, tx);

    // Step 0: prefetch rows R0+5..R0+8, then consume a1..a4.
    const float4 b1 = *reinterpret_cast<const float4*>(pl + (R0 + 5) * NMS_W);
    const float4 b2 = *reinterpret_cast<const float4*>(pl + (R0 + 6) * NMS_W);
    const float4 b3 = *reinterpret_cast<const float4*>(pl + (R0 + 7) * NMS_W);
    const float4 b4 = *reinterpret_cast<const float4*>(pl + (R0 + 8) * NMS_W);
    nms_step(a1, a2, a3, a4, vr, hA, hC, po, R0, tx);

    // Step 1: prefetch rows R0+9..R0+12, consume b1..b4.
    const float4 c1 = *reinterpret_cast<const float4*>(pl + (R0 +  9) * NMS_W);
    const float4 c2 = *reinterpret_cast<const float4*>(pl + (R0 + 10) * NMS_W);
    const float4 c3 = *reinterpret_cast<const float4*>(pl + (R0 + 11) * NMS_W);
    const float4 c4 = *reinterpret_cast<const float4*>(pl + (R0 + 12) * NMS_W);
    nms_step(b1, b2, b3, b4, vr, hA, hC, po, R0 + 4, tx);

    // Step 2: prefetch rows R0+13..R0+16 (last clamped at plane bottom),
    // consume c1..c4.
    const int rl = min(R0 + 16, NMS_H - 1);          // clamps only when R0 == 240
    const float4 d1 = *reinterpret_cast<const float4*>(pl + (R0 + 13) * NMS_W);
    const float4 d2 = *reinterpret_cast<const float4*>(pl + (R0 + 14) * NMS_W);
    const float4 d3 = *reinterpret_cast<const float4*>(pl + (R0 + 15) * NMS_W);
    const float4 d4 = *reinterpret_cast<const float4*>(pl + rl        * NMS_W);
    nms_step(c1, c2, c3, c4, vr, hA, hC, po, R0 + 8, tx);

    // Step 3: consume d1..d4 (no prefetch).
    nms_step(d1, d2, d3, d4, vr, hA, hC, po, R0 + 12, tx);
}

extern "C" void kernel_launch(void* const* d_in, const int* in_sizes, int n_in,
                              void* d_out, int out_size, void* d_ws, size_t ws_size,
                              hipStream_t stream) {
    const float* x = (const float*)d_in[0];
    float* out = (float*)d_out;

    // One wave per 16-row strip: 512 planes * 16 strips / 4 waves-per-block.
    dim3 block(256);
    dim3 grid(GRID_BLOCKS);
    nms2d_kernel<<<grid, block, 0, stream>>>(x, out);
}

// Round 4
// 221.025 us; speedup vs baseline: 1.0965x; 1.0965x over previous
//
#include <hip/hip_runtime.h>

// NMS 2D, 3x3 window, replicate padding, center excluded, max seeded with 0.
// x: (8, 64, 256, 256) fp32.  out[p] = x[p] if x[p] > max(0, 8 neighbors) else 0.
//
// R11 = R7 (best measured: ~65.8 us kernel) with the XCD swizzle removed.
// Session history (kernel-only time = bench - 2 x 80.4 us harness fills):
//   R7  (1 row/thread, loop-free, swizzle)   65.8 us   <- best
//   R8  (4 rows/thread, straight-line)       68.9 us   issue-halving NEUTRAL
//   R9  (R8 + nontemporal stores)            79.6 us   REGRESSED (lost L2 wc)
//   R10 (16-row pipelined strip, 2048 blks)  83.5 us   REGRESSED
// Perf tracks wave count monotonically; per-wave issue cost, cache policy,
// and intra-wave MLP are all exhausted (no counter saturated: VALU<=11%,
// HBM<=31%, occ<=72%). Max TLP (1 row/thread, 32768 blocks) wins.
// Swizzle removal: input (134 MB) is L3-fit (FETCH ~70MB < input), and the
// guide's m160 measured XCD swizzle COSTS ~2% in the L3-fit regime --
// plane-pinning concentrates the 3x halo read traffic on one XCD's L2/fabric
// port; round-robin spreads it, halo sharing falls through to shared L3.

#define NMS_H 256
#define NMS_W 256
#define PLANE (NMS_H * NMS_W)

typedef float f4_t __attribute__((ext_vector_type(4)));

struct HV {
    float4 h;   // horizontal max-of-3 per pixel (includes center)
    float4 lr;  // horizontal max of left+right only (center excluded)
};

__device__ __forceinline__ HV rowmax(const float4 v, const int tx) {
    float l = __shfl_up(v.w, 1, 64);    // last elem of lane tx-1
    float r = __shfl_down(v.x, 1, 64);  // first elem of lane tx+1
    if (tx == 0)  l = v.x;              // replicate pad left edge
    if (tx == 63) r = v.w;              // replicate pad right edge
    HV o;
    o.h.x = fmaxf(l,   fmaxf(v.x, v.y));
    o.h.y = fmaxf(v.x, fmaxf(v.y, v.z));
    o.h.z = fmaxf(v.y, fmaxf(v.z, v.w));
    o.h.w = fmaxf(v.z, fmaxf(v.w, r));
    o.lr.x = fmaxf(l,   v.y);
    o.lr.y = fmaxf(v.x, v.z);
    o.lr.z = fmaxf(v.y, v.w);
    o.lr.w = fmaxf(v.z, r);
    return o;
}

__global__ __launch_bounds__(256) void nms2d_kernel(const float* __restrict__ x,
                                                    float* __restrict__ out) {
    // No XCD swizzle: default round-robin dispatch spreads each plane's
    // halo-amplified read traffic across all 8 XCDs; shared L3 (256 MB,
    // input is fully resident) serves the cross-XCD halo re-reads.
    const int logical = blockIdx.x;

    const int plane_idx = logical >> 6;        // 512 planes
    const int rg        = logical & 63;        // 64 row-groups of 4 rows
    const int tx        = threadIdx.x & 63;    // float4 column-group
    const int r         = rg * 4 + (threadIdx.x >> 6);  // this wave's row
    const int col4      = tx * 4;

    const float* pl = x + (size_t)plane_idx * PLANE;

    // 3 independent clamped row loads — the thread's entire read set.
    const int rm = max(r - 1, 0);
    const int rp = min(r + 1, NMS_H - 1);
    const float4 va = *reinterpret_cast<const float4*>(pl + rm * NMS_W + col4);
    const float4 vc = *reinterpret_cast<const float4*>(pl + r  * NMS_W + col4);
    const float4 vb = *reinterpret_cast<const float4*>(pl + rp * NMS_W + col4);

    const HV ma = rowmax(va, tx);
    const HV mc = rowmax(vc, tx);
    const HV mb = rowmax(vb, tx);

    f4_t o;
    float m;
    m = fmaxf(0.0f, fmaxf(fmaxf(ma.h.x, mb.h.x), mc.lr.x)); o.x = (vc.x > m) ? vc.x : 0.0f;
    m = fmaxf(0.0f, fmaxf(fmaxf(ma.h.y, mb.h.y), mc.lr.y)); o.y = (vc.y > m) ? vc.y : 0.0f;
    m = fmaxf(0.0f, fmaxf(fmaxf(ma.h.z, mb.h.z), mc.lr.z)); o.z = (vc.z > m) ? vc.z : 0.0f;
    m = fmaxf(0.0f, fmaxf(fmaxf(ma.h.w, mb.h.w), mc.lr.w)); o.w = (vc.w > m) ? vc.w : 0.0f;

    *reinterpret_cast<f4_t*>(out + (size_t)plane_idx * PLANE + r * NMS_W + col4) = o;
}

extern "C" void kernel_launch(void* const* d_in, const int* in_sizes, int n_in,
                              void* d_out, int out_size, void* d_ws, size_t ws_size,
                              hipStream_t stream) {
    const float* x = (const float*)d_in[0];
    float* out = (float*)d_out;

    // One thread per output float4: 512 planes x 64 row-groups = 32768 blocks.
    dim3 block(256);
    dim3 grid(32768);
    nms2d_kernel<<<grid, block, 0, stream>>>(x, out);
}